// Round 1
// baseline (1705.288 us; speedup 1.0000x reference)
//
#include <hip/hip_runtime.h>

#define NI 50000
#define E_INTN 500000
#define E_BN 20000
#define E_CN 10000

// ---------------------------------------------------------------------------
// zero S (50000x128 floats) and the three count arrays (3x50000 ints)
__global__ __launch_bounds__(256) void zero_ws_kernel(float4* __restrict__ S4,
                                                      int* __restrict__ cnts) {
    int i = blockIdx.x * 256 + threadIdx.x;
    if (i < NI * 32) S4[i] = make_float4(0.f, 0.f, 0.f, 0.f);
    if (i < 3 * NI) cnts[i] = 0;
}

// ---------------------------------------------------------------------------
// per-target-node edge counts (mask-aware)
__global__ __launch_bounds__(256) void count_kernel(const int* __restrict__ ei,
                                                    const int* __restrict__ eb,
                                                    const int* __restrict__ ec,
                                                    const int* __restrict__ bidx,
                                                    const int* __restrict__ cidx,
                                                    int* __restrict__ ci,
                                                    int* __restrict__ cb,
                                                    int* __restrict__ cc) {
    int e = blockIdx.x * 256 + threadIdx.x;
    if (e < E_INTN) {
        atomicAdd(&ci[ei[E_INTN + e]], 1);
    } else if (e < E_INTN + E_BN) {
        int j = e - E_INTN;
        int s = eb[j];
        bool m = false;
#pragma unroll
        for (int k = 0; k < 16; ++k) m = m || (s == bidx[k]);
        if (m) atomicAdd(&cb[eb[E_BN + j]], 1);
    } else if (e < E_INTN + E_BN + E_CN) {
        int j = e - E_INTN - E_BN;
        int s = ec[j];
        bool m = false;
#pragma unroll
        for (int k = 0; k < 16; ++k) m = m || (s == cidx[k]);
        if (m) atomicAdd(&cc[ec[E_CN + j]], 1);
    }
}

// ---------------------------------------------------------------------------
// generic dual-input tiled GEMM on the vector ALU (no fp32 MFMA on CDNA4).
// C[m, n] (+)= rc[m]? * ( A1[m,:K1] . W1[n*w1s+w1o : +K1]
//                        + A2[m,:K2] . W2[n*w2s+w2o : +K2]  (if A2)
//                        + b1[n] + b2[n] )
// Tiles: BM=BN=32, 256 threads, 2x2 microtile, K fully LDS-resident.
// LDS stride 136 floats: 16B-aligned rows, 2-way-max bank aliasing (free).
__global__ __launch_bounds__(256) void gemm2_kernel(
    const float* __restrict__ A1, int K1,
    const float* __restrict__ W1, int w1s, int w1o,
    const float* __restrict__ A2, int K2,
    const float* __restrict__ W2, int w2s, int w2o,
    const float* __restrict__ b1, const float* __restrict__ b2,
    const int* __restrict__ rc, int accf,
    float* __restrict__ C, int M, int N, int ldc) {
    __shared__ float aT[32][136];
    __shared__ float wT[32][136];

    const int m0 = blockIdx.x * 32;
    const int n0 = blockIdx.y * 32;
    const int tid = threadIdx.x;
    const int ty = tid >> 4;   // 0..15
    const int tx = tid & 15;   // 0..15

    float acc00 = 0.f, acc01 = 0.f, acc10 = 0.f, acc11 = 0.f;

    for (int pass = 0; pass < 2; ++pass) {
        const float* Ap = (pass == 0) ? A1 : A2;
        if (Ap == nullptr) break;
        const float* Wp = (pass == 0) ? W1 : W2;
        const int K    = (pass == 0) ? K1 : K2;
        const int ws   = (pass == 0) ? w1s : w2s;
        const int wo   = (pass == 0) ? w1o : w2o;
        const int kf4 = K >> 2;

        if (pass == 1) __syncthreads();  // everyone done reading pass-0 tiles

        for (int idx = tid; idx < 32 * kf4; idx += 256) {
            int r = idx / kf4, c = (idx - r * kf4) * 4;
            int m = m0 + r;
            float4 v = make_float4(0.f, 0.f, 0.f, 0.f);
            if (m < M) v = *(const float4*)(Ap + (size_t)m * K + c);
            *(float4*)&aT[r][c] = v;
        }
        for (int idx = tid; idx < 32 * kf4; idx += 256) {
            int r = idx / kf4, c = (idx - r * kf4) * 4;
            float4 v = *(const float4*)(Wp + (size_t)(n0 + r) * ws + wo + c);
            *(float4*)&wT[r][c] = v;
        }
        __syncthreads();

        for (int c4 = 0; c4 < kf4; ++c4) {
            float4 a0  = *(float4*)&aT[ty][c4 * 4];
            float4 a1v = *(float4*)&aT[ty + 16][c4 * 4];
            float4 w0  = *(float4*)&wT[tx][c4 * 4];
            float4 w1v = *(float4*)&wT[tx + 16][c4 * 4];
            acc00 += a0.x * w0.x + a0.y * w0.y + a0.z * w0.z + a0.w * w0.w;
            acc01 += a0.x * w1v.x + a0.y * w1v.y + a0.z * w1v.z + a0.w * w1v.w;
            acc10 += a1v.x * w0.x + a1v.y * w0.y + a1v.z * w0.z + a1v.w * w0.w;
            acc11 += a1v.x * w1v.x + a1v.y * w1v.y + a1v.z * w1v.z + a1v.w * w1v.w;
        }
    }

    // epilogue
    float accs[2][2] = {{acc00, acc01}, {acc10, acc11}};
#pragma unroll
    for (int i = 0; i < 2; ++i) {
        int m = m0 + ty + i * 16;
        if (m >= M) continue;
        float rs = rc ? (float)rc[m] : 1.f;
#pragma unroll
        for (int j = 0; j < 2; ++j) {
            int n = n0 + tx + j * 16;
            float v = accs[i][j];
            if (b1) v += b1[n];
            if (b2) v += b2[n];
            v *= rs;
            float* p = C + (size_t)m * ldc + n;
            if (accf) *p += v; else *p = v;
        }
    }
}

// ---------------------------------------------------------------------------
// scatter: S[t] += row  (row = A[s] for interior, xbp[e]/ucp[e] for b/c edges)
// 32 lanes per edge, float4 per lane, hw fp32 atomics.
__global__ __launch_bounds__(256) void scatter_kernel(
    const float* __restrict__ A, const float* __restrict__ xbp,
    const float* __restrict__ ucp,
    const int* __restrict__ ei, const int* __restrict__ eb,
    const int* __restrict__ ec,
    const int* __restrict__ bidx, const int* __restrict__ cidx,
    float* __restrict__ S) {
    long long g = (long long)blockIdx.x * 256 + threadIdx.x;
    int edge = (int)(g >> 5);
    int lane = (int)(g & 31);
    const float* src;
    int t;
    if (edge < E_INTN) {
        int s = ei[edge];
        t = ei[E_INTN + edge];
        src = A + (size_t)s * 128;
    } else if (edge < E_INTN + E_BN) {
        int j = edge - E_INTN;
        int s = eb[j];
        bool m = false;
#pragma unroll
        for (int k = 0; k < 16; ++k) m = m || (s == bidx[k]);
        if (!m) return;
        t = eb[E_BN + j];
        src = xbp + (size_t)j * 128;
    } else if (edge < E_INTN + E_BN + E_CN) {
        int j = edge - E_INTN - E_BN;
        int s = ec[j];
        bool m = false;
#pragma unroll
        for (int k = 0; k < 16; ++k) m = m || (s == cidx[k]);
        if (!m) return;
        t = ec[E_CN + j];
        src = ucp + (size_t)j * 128;
    } else {
        return;
    }
    float4 v = ((const float4*)src)[lane];
    float* dst = S + (size_t)t * 128 + lane * 4;
    unsafeAtomicAdd(dst + 0, v.x);
    unsafeAtomicAdd(dst + 1, v.y);
    unsafeAtomicAdd(dst + 2, v.z);
    unsafeAtomicAdd(dst + 3, v.w);
}

// ---------------------------------------------------------------------------
// agg = S / max(cnt_total, 1), in place
__global__ __launch_bounds__(256) void agg_div_kernel(float4* __restrict__ S4,
                                                      const int* __restrict__ ci,
                                                      const int* __restrict__ cb,
                                                      const int* __restrict__ cc) {
    int idx = blockIdx.x * 256 + threadIdx.x;
    if (idx >= NI * 32) return;
    int n = idx >> 5;
    float denom = (float)(ci[n] + cb[n] + cc[n]);
    denom = fmaxf(denom, 1.f);
    float inv = 1.f / denom;
    float4 v = S4[idx];
    v.x *= inv; v.y *= inv; v.z *= inv; v.w *= inv;
    S4[idx] = v;
}

// ---------------------------------------------------------------------------
static inline void launch_gemm2(hipStream_t st,
                                const float* A1, int K1, const float* W1, int w1s, int w1o,
                                const float* A2, int K2, const float* W2, int w2s, int w2o,
                                const float* b1, const float* b2, const int* rc, int accf,
                                float* C, int M, int N, int ldc) {
    dim3 g((M + 31) / 32, N / 32);
    gemm2_kernel<<<g, dim3(256), 0, st>>>(A1, K1, W1, w1s, w1o, A2, K2, W2, w2s, w2o,
                                          b1, b2, rc, accf, C, M, N, ldc);
}

extern "C" void kernel_launch(void* const* d_in, const int* in_sizes, int n_in,
                              void* d_out, int out_size, void* d_ws, size_t ws_size,
                              hipStream_t stream) {
    const float* x    = (const float*)d_in[0];   // [50000,128]
    const float* xb   = (const float*)d_in[1];   // [20000,128]
    const float* u    = (const float*)d_in[2];   // [10000,64]
    const int*   ei   = (const int*)d_in[3];     // [2,500000]
    const int*   eb   = (const int*)d_in[4];     // [2,20000]
    const int*   ec   = (const int*)d_in[5];     // [2,10000]
    const int*   bidx = (const int*)d_in[6];     // [16]
    const int*   cidx = (const int*)d_in[7];     // [16]
    const float* W_ii = (const float*)d_in[8];   const float* b_ii = (const float*)d_in[9];
    const float* W_bi = (const float*)d_in[10];  const float* b_bi = (const float*)d_in[11];
    const float* W_ci = (const float*)d_in[12];  const float* b_ci = (const float*)d_in[13];
    const float* W_bb = (const float*)d_in[14];  const float* b_bb = (const float*)d_in[15];
    const float* W_cc = (const float*)d_in[16];  const float* b_cc = (const float*)d_in[17];
    const float* W_im = (const float*)d_in[18];  const float* b_im = (const float*)d_in[19];
    const float* W_is = (const float*)d_in[20];  const float* b_is = (const float*)d_in[21];
    const float* W_bm = (const float*)d_in[22];  const float* b_bm = (const float*)d_in[23];
    const float* W_bs = (const float*)d_in[24];  const float* b_bs = (const float*)d_in[25];
    const float* W_cm = (const float*)d_in[26];  const float* b_cm = (const float*)d_in[27];
    const float* W_cs = (const float*)d_in[28];  const float* b_cs = (const float*)d_in[29];

    float* out = (float*)d_out;
    float* ws  = (float*)d_ws;

    // workspace layout (floats): total = 16,790,000 floats = 67.2 MB
    float* A   = ws;               // [50000,128]  A-table: x @ W_ii[:, :128].T
    float* S   = ws + 6400000;     // [50000,128]  scatter accumulator -> agg
    float* xbp = ws + 12800000;    // [20000,128]  x_bound @ W_bi[:, :128].T ; reused as sb
    float* ucp = ws + 15360000;    // [10000,128]  u @ W_ci[:, :64].T       ; reused as sc
    int*   ci  = (int*)(ws + 16640000);
    int*   cb  = ci + NI;
    int*   cc  = cb + NI;

    // 1. zero S + counts
    zero_ws_kernel<<<dim3((NI * 32 + 255) / 256), dim3(256), 0, stream>>>((float4*)S, ci);
    // 2. per-node edge counts
    count_kernel<<<dim3((E_INTN + E_BN + E_CN + 255) / 256), dim3(256), 0, stream>>>(
        ei, eb, ec, bidx, cidx, ci, cb, cc);
    // 3. A = x @ W_ii[:, :128].T            (no bias: b_ii folded via counts)
    launch_gemm2(stream, x, 128, W_ii, 256, 0, nullptr, 0, nullptr, 0, 0,
                 nullptr, nullptr, nullptr, 0, A, NI, 128, 128);
    // 4-6. S += cnt_* ( x @ W_*B.T + b_* )
    launch_gemm2(stream, x, 128, W_ii, 256, 128, nullptr, 0, nullptr, 0, 0,
                 b_ii, nullptr, ci, 1, S, NI, 128, 128);
    launch_gemm2(stream, x, 128, W_bi, 256, 128, nullptr, 0, nullptr, 0, 0,
                 b_bi, nullptr, cb, 1, S, NI, 128, 128);
    launch_gemm2(stream, x, 128, W_ci, 192, 64, nullptr, 0, nullptr, 0, 0,
                 b_ci, nullptr, cc, 1, S, NI, 128, 128);
    // 7. xbp = x_bound @ W_bi[:, :128].T
    launch_gemm2(stream, xb, 128, W_bi, 256, 0, nullptr, 0, nullptr, 0, 0,
                 nullptr, nullptr, nullptr, 0, xbp, E_BN, 128, 128);
    // 8. ucp = u @ W_ci[:, :64].T
    launch_gemm2(stream, u, 64, W_ci, 192, 0, nullptr, 0, nullptr, 0, 0,
                 nullptr, nullptr, nullptr, 0, ucp, E_CN, 128, 128);
    // 9. scatter rows into S (atomics)
    {
        long long total = (long long)(E_INTN + E_BN + E_CN) * 32;
        scatter_kernel<<<dim3((unsigned)((total + 255) / 256)), dim3(256), 0, stream>>>(
            A, xbp, ucp, ei, eb, ec, bidx, cidx, S);
    }
    // 10. S -> agg (divide by counts)
    agg_div_kernel<<<dim3((NI * 32 + 255) / 256), dim3(256), 0, stream>>>(
        (float4*)S, ci, cb, cc);
    // 11. interior_update = x@W_is.T + b_is + agg@W_im.T + b_im
    launch_gemm2(stream, x, 128, W_is, 128, 0, S, 128, W_im, 128, 0,
                 b_is, b_im, nullptr, 0, out, NI, 256, 256);
    // 12. sb = x_bound@(W_bbA+W_bbB).T + b_bb   (into xbp space)
    launch_gemm2(stream, xb, 128, W_bb, 256, 0, xb, 128, W_bb, 256, 128,
                 b_bb, nullptr, nullptr, 0, xbp, E_BN, 128, 128);
    // 13. boundary_update = x_bound@W_bs.T + b_bs + sb@W_bm.T + b_bm
    launch_gemm2(stream, xb, 128, W_bs, 128, 0, xbp, 128, W_bm, 128, 0,
                 b_bs, b_bm, nullptr, 0, out + (size_t)NI * 256, E_BN, 256, 256);
    // 14. sc = u@(W_ccA+W_ccB).T + b_cc        (into ucp space)
    launch_gemm2(stream, u, 64, W_cc, 128, 0, u, 64, W_cc, 128, 64,
                 b_cc, nullptr, nullptr, 0, ucp, E_CN, 128, 128);
    // 15. control_update = u@W_cs.T + b_cs + sc@W_cm.T + b_cm
    launch_gemm2(stream, u, 64, W_cs, 64, 0, ucp, 128, W_cm, 128, 0,
                 b_cs, b_cm, nullptr, 0, out + (size_t)(NI + E_BN) * 256, E_CN, 256, 256);
}

// Round 2
// 1094.350 us; speedup vs baseline: 1.5583x; 1.5583x over previous
//
#include <hip/hip_runtime.h>

#define NI 50000
#define E_INTN 500000
#define E_BN 20000
#define E_CN 10000
#define E_TOT (E_INTN + E_BN + E_CN)

// ---------------------------------------------------------------------------
// zero S (50000x128 floats) and the three count arrays (3x50000 ints)
__global__ __launch_bounds__(256) void zero_ws_kernel(float4* __restrict__ S4,
                                                      int* __restrict__ cnts) {
    int i = blockIdx.x * 256 + threadIdx.x;
    if (i < NI * 32) S4[i] = make_float4(0.f, 0.f, 0.f, 0.f);
    if (i < 3 * NI) cnts[i] = 0;
}

// ---------------------------------------------------------------------------
// per-target-node edge counts (mask-aware)
__global__ __launch_bounds__(256) void count_kernel(const int* __restrict__ ei,
                                                    const int* __restrict__ eb,
                                                    const int* __restrict__ ec,
                                                    const int* __restrict__ bidx,
                                                    const int* __restrict__ cidx,
                                                    int* __restrict__ ci,
                                                    int* __restrict__ cb,
                                                    int* __restrict__ cc) {
    int e = blockIdx.x * 256 + threadIdx.x;
    if (e < E_INTN) {
        atomicAdd(&ci[ei[E_INTN + e]], 1);
    } else if (e < E_INTN + E_BN) {
        int j = e - E_INTN;
        int s = eb[j];
        bool m = false;
#pragma unroll
        for (int k = 0; k < 16; ++k) m = m || (s == bidx[k]);
        if (m) atomicAdd(&cb[eb[E_BN + j]], 1);
    } else if (e < E_TOT) {
        int j = e - E_INTN - E_BN;
        int s = ec[j];
        bool m = false;
#pragma unroll
        for (int k = 0; k < 16; ++k) m = m || (s == cidx[k]);
        if (m) atomicAdd(&cc[ec[E_CN + j]], 1);
    }
}

// ---------------------------------------------------------------------------
// single-block exclusive scan of tot[n]=ci+cb+cc over NI entries
// writes offsets[] and an identical cursor[] for the fill pass
__global__ __launch_bounds__(256) void scan_kernel(const int* __restrict__ ci,
                                                   const int* __restrict__ cb,
                                                   const int* __restrict__ cc,
                                                   int* __restrict__ offsets,
                                                   int* __restrict__ cursor) {
    __shared__ int sums[256];
    const int t = threadIdx.x;
    const int CH = (NI + 255) / 256;  // 196
    int lo = t * CH, hi = lo + CH;
    if (hi > NI) hi = NI;
    int s = 0;
    for (int n = lo; n < hi; ++n) s += ci[n] + cb[n] + cc[n];
    sums[t] = s;
    __syncthreads();
    // Hillis-Steele inclusive scan
    for (int d = 1; d < 256; d <<= 1) {
        int v = (t >= d) ? sums[t - d] : 0;
        __syncthreads();
        sums[t] += v;
        __syncthreads();
    }
    int run = (t > 0) ? sums[t - 1] : 0;
    for (int n = lo; n < hi; ++n) {
        offsets[n] = run;
        cursor[n] = run;
        run += ci[n] + cb[n] + cc[n];
    }
}

// ---------------------------------------------------------------------------
// CSR fill: eids[slot] = row index into the virtual table [A | xbp | ucp]
__global__ __launch_bounds__(256) void fill_kernel(const int* __restrict__ ei,
                                                   const int* __restrict__ eb,
                                                   const int* __restrict__ ec,
                                                   const int* __restrict__ bidx,
                                                   const int* __restrict__ cidx,
                                                   int* __restrict__ cursor,
                                                   int* __restrict__ eids) {
    int e = blockIdx.x * 256 + threadIdx.x;
    int t, payload;
    if (e < E_INTN) {
        t = ei[E_INTN + e];
        payload = ei[e];
    } else if (e < E_INTN + E_BN) {
        int j = e - E_INTN;
        int s = eb[j];
        bool m = false;
#pragma unroll
        for (int k = 0; k < 16; ++k) m = m || (s == bidx[k]);
        if (!m) return;
        t = eb[E_BN + j];
        payload = NI + j;
    } else if (e < E_TOT) {
        int j = e - E_INTN - E_BN;
        int s = ec[j];
        bool m = false;
#pragma unroll
        for (int k = 0; k < 16; ++k) m = m || (s == cidx[k]);
        if (!m) return;
        t = ec[E_CN + j];
        payload = NI + E_BN + j;
    } else {
        return;
    }
    int idx = atomicAdd(&cursor[t], 1);
    eids[idx] = payload;
}

// ---------------------------------------------------------------------------
// gather-sum: each node owns its row. 32 lanes per node, float4 per lane.
// S already holds the count-weighted terms; add CSR edge rows, divide.
__global__ __launch_bounds__(256) void gather_kernel(const float4* __restrict__ T4,
                                                     const int* __restrict__ offsets,
                                                     const int* __restrict__ ci,
                                                     const int* __restrict__ cb,
                                                     const int* __restrict__ cc,
                                                     const int* __restrict__ eids,
                                                     float4* __restrict__ S4) {
    int g = blockIdx.x * 256 + threadIdx.x;
    int n = g >> 5;
    int lane = g & 31;
    if (n >= NI) return;
    int off = offsets[n];
    int deg = ci[n] + cb[n] + cc[n];
    float4 acc = S4[(size_t)n * 32 + lane];
    for (int k = 0; k < deg; ++k) {
        int eid = eids[off + k];
        float4 v = T4[(size_t)eid * 32 + lane];
        acc.x += v.x; acc.y += v.y; acc.z += v.z; acc.w += v.w;
    }
    float inv = 1.f / fmaxf((float)deg, 1.f);
    acc.x *= inv; acc.y *= inv; acc.z *= inv; acc.w *= inv;
    S4[(size_t)n * 32 + lane] = acc;
}

// ---------------------------------------------------------------------------
// generic dual-input tiled GEMM on the vector ALU (no fp32 MFMA on CDNA4).
__global__ __launch_bounds__(256) void gemm2_kernel(
    const float* __restrict__ A1, int K1,
    const float* __restrict__ W1, int w1s, int w1o,
    const float* __restrict__ A2, int K2,
    const float* __restrict__ W2, int w2s, int w2o,
    const float* __restrict__ b1, const float* __restrict__ b2,
    const int* __restrict__ rc, int accf,
    float* __restrict__ C, int M, int N, int ldc) {
    __shared__ float aT[32][136];
    __shared__ float wT[32][136];

    const int m0 = blockIdx.x * 32;
    const int n0 = blockIdx.y * 32;
    const int tid = threadIdx.x;
    const int ty = tid >> 4;
    const int tx = tid & 15;

    float acc00 = 0.f, acc01 = 0.f, acc10 = 0.f, acc11 = 0.f;

    for (int pass = 0; pass < 2; ++pass) {
        const float* Ap = (pass == 0) ? A1 : A2;
        if (Ap == nullptr) break;
        const float* Wp = (pass == 0) ? W1 : W2;
        const int K  = (pass == 0) ? K1 : K2;
        const int ws = (pass == 0) ? w1s : w2s;
        const int wo = (pass == 0) ? w1o : w2o;
        const int kf4 = K >> 2;

        if (pass == 1) __syncthreads();

        for (int idx = tid; idx < 32 * kf4; idx += 256) {
            int r = idx / kf4, c = (idx - r * kf4) * 4;
            int m = m0 + r;
            float4 v = make_float4(0.f, 0.f, 0.f, 0.f);
            if (m < M) v = *(const float4*)(Ap + (size_t)m * K + c);
            *(float4*)&aT[r][c] = v;
        }
        for (int idx = tid; idx < 32 * kf4; idx += 256) {
            int r = idx / kf4, c = (idx - r * kf4) * 4;
            float4 v = *(const float4*)(Wp + (size_t)(n0 + r) * ws + wo + c);
            *(float4*)&wT[r][c] = v;
        }
        __syncthreads();

        for (int c4 = 0; c4 < kf4; ++c4) {
            float4 a0  = *(float4*)&aT[ty][c4 * 4];
            float4 a1v = *(float4*)&aT[ty + 16][c4 * 4];
            float4 w0  = *(float4*)&wT[tx][c4 * 4];
            float4 w1v = *(float4*)&wT[tx + 16][c4 * 4];
            acc00 += a0.x * w0.x + a0.y * w0.y + a0.z * w0.z + a0.w * w0.w;
            acc01 += a0.x * w1v.x + a0.y * w1v.y + a0.z * w1v.z + a0.w * w1v.w;
            acc10 += a1v.x * w0.x + a1v.y * w0.y + a1v.z * w0.z + a1v.w * w0.w;
            acc11 += a1v.x * w1v.x + a1v.y * w1v.y + a1v.z * w1v.z + a1v.w * w1v.w;
        }
    }

    float accs[2][2] = {{acc00, acc01}, {acc10, acc11}};
#pragma unroll
    for (int i = 0; i < 2; ++i) {
        int m = m0 + ty + i * 16;
        if (m >= M) continue;
        float rs = rc ? (float)rc[m] : 1.f;
#pragma unroll
        for (int j = 0; j < 2; ++j) {
            int n = n0 + tx + j * 16;
            float v = accs[i][j];
            if (b1) v += b1[n];
            if (b2) v += b2[n];
            v *= rs;
            float* p = C + (size_t)m * ldc + n;
            if (accf) *p += v; else *p = v;
        }
    }
}

// ---------------------------------------------------------------------------
static inline void launch_gemm2(hipStream_t st,
                                const float* A1, int K1, const float* W1, int w1s, int w1o,
                                const float* A2, int K2, const float* W2, int w2s, int w2o,
                                const float* b1, const float* b2, const int* rc, int accf,
                                float* C, int M, int N, int ldc) {
    dim3 g((M + 31) / 32, N / 32);
    gemm2_kernel<<<g, dim3(256), 0, st>>>(A1, K1, W1, w1s, w1o, A2, K2, W2, w2s, w2o,
                                          b1, b2, rc, accf, C, M, N, ldc);
}

extern "C" void kernel_launch(void* const* d_in, const int* in_sizes, int n_in,
                              void* d_out, int out_size, void* d_ws, size_t ws_size,
                              hipStream_t stream) {
    const float* x    = (const float*)d_in[0];
    const float* xb   = (const float*)d_in[1];
    const float* u    = (const float*)d_in[2];
    const int*   ei   = (const int*)d_in[3];
    const int*   eb   = (const int*)d_in[4];
    const int*   ec   = (const int*)d_in[5];
    const int*   bidx = (const int*)d_in[6];
    const int*   cidx = (const int*)d_in[7];
    const float* W_ii = (const float*)d_in[8];   const float* b_ii = (const float*)d_in[9];
    const float* W_bi = (const float*)d_in[10];  const float* b_bi = (const float*)d_in[11];
    const float* W_ci = (const float*)d_in[12];  const float* b_ci = (const float*)d_in[13];
    const float* W_bb = (const float*)d_in[14];  const float* b_bb = (const float*)d_in[15];
    const float* W_cc = (const float*)d_in[16];  const float* b_cc = (const float*)d_in[17];
    const float* W_im = (const float*)d_in[18];  const float* b_im = (const float*)d_in[19];
    const float* W_is = (const float*)d_in[20];  const float* b_is = (const float*)d_in[21];
    const float* W_bm = (const float*)d_in[22];  const float* b_bm = (const float*)d_in[23];
    const float* W_bs = (const float*)d_in[24];  const float* b_bs = (const float*)d_in[25];
    const float* W_cm = (const float*)d_in[26];  const float* b_cm = (const float*)d_in[27];
    const float* W_cs = (const float*)d_in[28];  const float* b_cs = (const float*)d_in[29];

    float* out = (float*)d_out;
    float* ws  = (float*)d_ws;

    // ws layout (floats), virtual table T = [A | xbp | ucp] contiguous:
    float* A   = ws;               // [50000,128] rows 0..49999 of T
    float* xbp = ws + 6400000;     // [20000,128] rows 50000..69999 ; reused as sb
    float* ucp = ws + 8960000;     // [10000,128] rows 70000..79999 ; reused as sc
    float* S   = ws + 10240000;    // [50000,128] accumulator -> agg
    // total ws use: 16,640,000 floats = 66.56 MB (<= round-0's proven 67.2 MB)

    // int scratch lives in d_out's boundary region (written only at step 13,
    // after every CSR consumer has finished):
    int* ints    = (int*)(out + (size_t)NI * 256);
    int* ci      = ints;            // [50000]
    int* cb      = ci + NI;         // [50000]
    int* cc      = cb + NI;         // [50000]
    int* offsets = cc + NI;         // [50000]
    int* cursor  = offsets + NI;    // [50000]
    int* eids    = cursor + NI;     // [530000]  (total = 780k ints = 3.1 MB < 20.5 MB region)

    // 1. zero S + counts
    zero_ws_kernel<<<dim3((NI * 32 + 255) / 256), dim3(256), 0, stream>>>((float4*)S, ci);
    // 2. per-node edge counts
    count_kernel<<<dim3((E_TOT + 255) / 256), dim3(256), 0, stream>>>(
        ei, eb, ec, bidx, cidx, ci, cb, cc);
    // 3. exclusive scan -> offsets, cursor
    scan_kernel<<<dim3(1), dim3(256), 0, stream>>>(ci, cb, cc, offsets, cursor);
    // 4. CSR fill
    fill_kernel<<<dim3((E_TOT + 255) / 256), dim3(256), 0, stream>>>(
        ei, eb, ec, bidx, cidx, cursor, eids);
    // 5. A = x @ W_ii[:, :128].T
    launch_gemm2(stream, x, 128, W_ii, 256, 0, nullptr, 0, nullptr, 0, 0,
                 nullptr, nullptr, nullptr, 0, A, NI, 128, 128);
    // 6-8. S += cnt_* ( x @ W_*B.T + b_* )
    launch_gemm2(stream, x, 128, W_ii, 256, 128, nullptr, 0, nullptr, 0, 0,
                 b_ii, nullptr, ci, 1, S, NI, 128, 128);
    launch_gemm2(stream, x, 128, W_bi, 256, 128, nullptr, 0, nullptr, 0, 0,
                 b_bi, nullptr, cb, 1, S, NI, 128, 128);
    launch_gemm2(stream, x, 128, W_ci, 192, 64, nullptr, 0, nullptr, 0, 0,
                 b_ci, nullptr, cc, 1, S, NI, 128, 128);
    // 9. xbp = x_bound @ W_bi[:, :128].T
    launch_gemm2(stream, xb, 128, W_bi, 256, 0, nullptr, 0, nullptr, 0, 0,
                 nullptr, nullptr, nullptr, 0, xbp, E_BN, 128, 128);
    // 10. ucp = u @ W_ci[:, :64].T
    launch_gemm2(stream, u, 64, W_ci, 192, 0, nullptr, 0, nullptr, 0, 0,
                 nullptr, nullptr, nullptr, 0, ucp, E_CN, 128, 128);
    // 11. gather-sum CSR rows into S, divide by counts (agg finalized)
    gather_kernel<<<dim3((NI * 32 + 255) / 256), dim3(256), 0, stream>>>(
        (const float4*)A, offsets, ci, cb, cc, eids, (float4*)S);
    // 12. interior_update = x@W_is.T + b_is + agg@W_im.T + b_im
    launch_gemm2(stream, x, 128, W_is, 128, 0, S, 128, W_im, 128, 0,
                 b_is, b_im, nullptr, 0, out, NI, 256, 256);
    // 13. sb = x_bound@(W_bbA+W_bbB).T + b_bb   (into xbp space)
    launch_gemm2(stream, xb, 128, W_bb, 256, 0, xb, 128, W_bb, 256, 128,
                 b_bb, nullptr, nullptr, 0, xbp, E_BN, 128, 128);
    // 14. boundary_update = x_bound@W_bs.T + b_bs + sb@W_bm.T + b_bm
    //     (overwrites the int scratch region -- all CSR consumers are done)
    launch_gemm2(stream, xb, 128, W_bs, 128, 0, xbp, 128, W_bm, 128, 0,
                 b_bs, b_bm, nullptr, 0, out + (size_t)NI * 256, E_BN, 256, 256);
    // 15. sc = u@(W_ccA+W_ccB).T + b_cc        (into ucp space)
    launch_gemm2(stream, u, 64, W_cc, 128, 0, u, 64, W_cc, 128, 64,
                 b_cc, nullptr, nullptr, 0, ucp, E_CN, 128, 128);
    // 16. control_update = u@W_cs.T + b_cs + sc@W_cm.T + b_cm
    launch_gemm2(stream, u, 64, W_cs, 64, 0, ucp, 128, W_cm, 128, 0,
                 b_cs, b_cm, nullptr, 0, out + (size_t)(NI + E_BN) * 256, E_CN, 256, 256);
}

// Round 3
// 450.151 us; speedup vs baseline: 3.7883x; 2.4311x over previous
//
#include <hip/hip_runtime.h>

#define NI 50000
#define E_INTN 500000
#define E_BN 20000
#define E_CN 10000
#define E_TOT (E_INTN + E_BN + E_CN)

typedef __attribute__((ext_vector_type(8))) short bf16x8_t;
typedef __attribute__((ext_vector_type(4))) float f32x4_t;

__device__ __forceinline__ unsigned short f2bf(float f) {
    unsigned int u = __float_as_uint(f);
    unsigned int r = (u + 0x7FFFu + ((u >> 16) & 1u)) >> 16;
    return (unsigned short)r;
}
__device__ __forceinline__ float bf2f(unsigned int h) {
    return __uint_as_float(h << 16);
}

// ---------------------------------------------------------------------------
// weight prep: fp32 -> packed bf16 [N x K], optional second-slice add (off2)
struct WJob { const float* src; int stride, off, off2, N, K, dstOff; };
struct WJobs { WJob j[14]; };

__global__ __launch_bounds__(256) void prep_weights_kernel(WJobs jobs,
                                                           unsigned short* wbuf) {
    WJob jb = jobs.j[blockIdx.y];
    int idx = blockIdx.x * 256 + threadIdx.x;
    if (idx >= jb.N * jb.K) return;
    int n = idx / jb.K;
    int k = idx - n * jb.K;
    float v = jb.src[(size_t)n * jb.stride + jb.off + k];
    if (jb.off2 >= 0) v += jb.src[(size_t)n * jb.stride + jb.off2 + k];
    wbuf[jb.dstOff + (size_t)n * jb.K + k] = f2bf(v);
}

// ---------------------------------------------------------------------------
// convert x (6.4M), xb (2.56M), u (0.64M) fp32 -> bf16, float4-granular
__global__ __launch_bounds__(256) void conv_inputs_kernel(const float4* __restrict__ x,
                                                          const float4* __restrict__ xb,
                                                          const float4* __restrict__ u,
                                                          ushort4* __restrict__ x_bf,
                                                          ushort4* __restrict__ xb_bf,
                                                          ushort4* __restrict__ u_bf) {
    int g = blockIdx.x * 256 + threadIdx.x;
    const float4* src; ushort4* dst; int i;
    if (g < 1600000)      { src = x;  dst = x_bf;  i = g; }
    else if (g < 2240000) { src = xb; dst = xb_bf; i = g - 1600000; }
    else if (g < 2400000) { src = u;  dst = u_bf;  i = g - 2240000; }
    else return;
    float4 v = src[i];
    ushort4 o;
    o.x = f2bf(v.x); o.y = f2bf(v.y); o.z = f2bf(v.z); o.w = f2bf(v.w);
    dst[i] = o;
}

// ---------------------------------------------------------------------------
__global__ __launch_bounds__(256) void zero_counts_kernel(int* __restrict__ c) {
    int i = blockIdx.x * 256 + threadIdx.x;
    if (i < 3 * NI) c[i] = 0;
}

__global__ __launch_bounds__(256) void count_kernel(const int* __restrict__ ei,
                                                    const int* __restrict__ eb,
                                                    const int* __restrict__ ec,
                                                    const int* __restrict__ bidx,
                                                    const int* __restrict__ cidx,
                                                    int* __restrict__ ci,
                                                    int* __restrict__ cb,
                                                    int* __restrict__ cc) {
    int e = blockIdx.x * 256 + threadIdx.x;
    if (e < E_INTN) {
        atomicAdd(&ci[ei[E_INTN + e]], 1);
    } else if (e < E_INTN + E_BN) {
        int j = e - E_INTN;
        int s = eb[j];
        bool m = false;
#pragma unroll
        for (int k = 0; k < 16; ++k) m = m || (s == bidx[k]);
        if (m) atomicAdd(&cb[eb[E_BN + j]], 1);
    } else if (e < E_TOT) {
        int j = e - E_INTN - E_BN;
        int s = ec[j];
        bool m = false;
#pragma unroll
        for (int k = 0; k < 16; ++k) m = m || (s == cidx[k]);
        if (m) atomicAdd(&cc[ec[E_CN + j]], 1);
    }
}

// ---------------------------------------------------------------------------
// 3-phase parallel exclusive scan of deg over NI nodes
#define SCAN_NB 196   // ceil(50000/256)

__global__ __launch_bounds__(256) void scan1_kernel(const int* __restrict__ ci,
                                                    const int* __restrict__ cb,
                                                    const int* __restrict__ cc,
                                                    int* __restrict__ bsum) {
    __shared__ int sm[256];
    int n = blockIdx.x * 256 + threadIdx.x;
    int d = (n < NI) ? ci[n] + cb[n] + cc[n] : 0;
    sm[threadIdx.x] = d;
    __syncthreads();
    for (int s = 128; s > 0; s >>= 1) {
        if (threadIdx.x < s) sm[threadIdx.x] += sm[threadIdx.x + s];
        __syncthreads();
    }
    if (threadIdx.x == 0) bsum[blockIdx.x] = sm[0];
}

__global__ __launch_bounds__(256) void scan2_kernel(const int* __restrict__ bsum,
                                                    int* __restrict__ ebase) {
    __shared__ int sm[256];
    int t = threadIdx.x;
    sm[t] = (t < SCAN_NB) ? bsum[t] : 0;
    __syncthreads();
    for (int d = 1; d < 256; d <<= 1) {
        int v = (t >= d) ? sm[t - d] : 0;
        __syncthreads();
        sm[t] += v;
        __syncthreads();
    }
    ebase[t] = (t > 0) ? sm[t - 1] : 0;
}

__global__ __launch_bounds__(256) void scan3_kernel(const int* __restrict__ ci,
                                                    const int* __restrict__ cb,
                                                    const int* __restrict__ cc,
                                                    const int* __restrict__ ebase,
                                                    int* __restrict__ offsets,
                                                    int* __restrict__ cursor) {
    __shared__ int sm[256];
    int t = threadIdx.x;
    int n = blockIdx.x * 256 + t;
    int d = (n < NI) ? ci[n] + cb[n] + cc[n] : 0;
    sm[t] = d;
    __syncthreads();
    for (int dd = 1; dd < 256; dd <<= 1) {
        int v = (t >= dd) ? sm[t - dd] : 0;
        __syncthreads();
        sm[t] += v;
        __syncthreads();
    }
    if (n < NI) {
        int excl = sm[t] - d + ebase[blockIdx.x];
        offsets[n] = excl;
        cursor[n] = excl;
    }
}

// ---------------------------------------------------------------------------
__global__ __launch_bounds__(256) void fill_kernel(const int* __restrict__ ei,
                                                   const int* __restrict__ eb,
                                                   const int* __restrict__ ec,
                                                   const int* __restrict__ bidx,
                                                   const int* __restrict__ cidx,
                                                   int* __restrict__ cursor,
                                                   int* __restrict__ eids) {
    int e = blockIdx.x * 256 + threadIdx.x;
    int t, payload;
    if (e < E_INTN) {
        t = ei[E_INTN + e];
        payload = ei[e];
    } else if (e < E_INTN + E_BN) {
        int j = e - E_INTN;
        int s = eb[j];
        bool m = false;
#pragma unroll
        for (int k = 0; k < 16; ++k) m = m || (s == bidx[k]);
        if (!m) return;
        t = eb[E_BN + j];
        payload = NI + j;
    } else if (e < E_TOT) {
        int j = e - E_INTN - E_BN;
        int s = ec[j];
        bool m = false;
#pragma unroll
        for (int k = 0; k < 16; ++k) m = m || (s == cidx[k]);
        if (!m) return;
        t = ec[E_CN + j];
        payload = NI + E_BN + j;
    } else {
        return;
    }
    int idx = atomicAdd(&cursor[t], 1);
    eids[idx] = payload;
}

// ---------------------------------------------------------------------------
// gather: 16 lanes/node, 8 floats/lane. S holds count-weighted terms (fp32).
// Adds CSR edge rows (bf16 tables), divides, writes agg bf16 in-place into
// the first 256B of each 512B S row (=> agg has row stride 256 ushorts).
__global__ __launch_bounds__(256) void gather_kernel(
    const unsigned short* __restrict__ Abf,
    const unsigned short* __restrict__ xbp,
    const unsigned short* __restrict__ ucp,
    const int* __restrict__ offsets,
    const int* __restrict__ ci, const int* __restrict__ cb,
    const int* __restrict__ cc, const int* __restrict__ eids,
    float* __restrict__ S) {
    int g = blockIdx.x * 256 + threadIdx.x;
    int n = g >> 4;
    int lane = g & 15;
    if (n >= NI) return;
    int off = offsets[n];
    int deg = ci[n] + cb[n] + cc[n];
    const float* srow = S + (size_t)n * 128 + lane * 8;
    float acc[8];
#pragma unroll
    for (int t = 0; t < 8; ++t) acc[t] = srow[t];
    for (int k = 0; k < deg; ++k) {
        int eid = eids[off + k];
        const unsigned short* row =
            (eid < NI) ? Abf + (size_t)eid * 128
          : (eid < NI + E_BN) ? xbp + (size_t)(eid - NI) * 128
          : ucp + (size_t)(eid - NI - E_BN) * 128;
        uint4 d = *(const uint4*)(row + lane * 8);
        acc[0] += bf2f(d.x & 0xffff); acc[1] += bf2f(d.x >> 16);
        acc[2] += bf2f(d.y & 0xffff); acc[3] += bf2f(d.y >> 16);
        acc[4] += bf2f(d.z & 0xffff); acc[5] += bf2f(d.z >> 16);
        acc[6] += bf2f(d.w & 0xffff); acc[7] += bf2f(d.w >> 16);
    }
    float inv = 1.f / fmaxf((float)deg, 1.f);
    uint4 o;
    o.x = (unsigned)f2bf(acc[0] * inv) | ((unsigned)f2bf(acc[1] * inv) << 16);
    o.y = (unsigned)f2bf(acc[2] * inv) | ((unsigned)f2bf(acc[3] * inv) << 16);
    o.z = (unsigned)f2bf(acc[4] * inv) | ((unsigned)f2bf(acc[5] * inv) << 16);
    o.w = (unsigned)f2bf(acc[6] * inv) | ((unsigned)f2bf(acc[7] * inv) << 16);
    unsigned short* arow = (unsigned short*)(S + (size_t)n * 128) + lane * 8;
    *(uint4*)arow = o;
}

// ---------------------------------------------------------------------------
// bf16 MFMA GEMM: C[M,N] = A1@W1.T (+ A2@W2.T) (+b1+b2), opt cnt-scale,
// opt fp32-accumulate, opt bf16 output. A row-major bf16 (stride lda),
// W packed [N x K] bf16. 128x128 block tile, BK=32, 4 waves, 4x4 MFMA tiles.
// N must be a multiple of 128 (gridDim.y = N/128); K multiple of 32.
__global__ __launch_bounds__(256) void mfma_gemm_kernel(
    const unsigned short* __restrict__ A1, int lda1, int K1,
    const unsigned short* __restrict__ W1,
    const unsigned short* __restrict__ A2, int lda2, int K2,
    const unsigned short* __restrict__ W2,
    const float* __restrict__ b1, const float* __restrict__ b2,
    const int* __restrict__ cnt, int accf, int outbf,
    void* __restrict__ C, int M, int ldc) {
    __shared__ __align__(16) unsigned short As[128][40];
    __shared__ __align__(16) unsigned short Wsh[128][40];

    const int m0 = blockIdx.x * 128;
    const int n0 = blockIdx.y * 128;
    const int tid = threadIdx.x;
    const int wid = tid >> 6;
    const int wm = wid >> 1, wn = wid & 1;
    const int lane = tid & 63;
    const int lr = lane & 15;
    const int k0 = (lane >> 4) * 8;

    f32x4_t acc[4][4];
#pragma unroll
    for (int i = 0; i < 4; ++i)
#pragma unroll
        for (int j = 0; j < 4; ++j) {
            f32x4_t z = {0.f, 0.f, 0.f, 0.f};
            acc[i][j] = z;
        }

    for (int pass = 0; pass < 2; ++pass) {
        const unsigned short* Ap = (pass == 0) ? A1 : A2;
        if (Ap == nullptr) break;
        const unsigned short* Wp = (pass == 0) ? W1 : W2;
        const int lda = (pass == 0) ? lda1 : lda2;
        const int K   = (pass == 0) ? K1 : K2;
        const int nch = K >> 5;

        for (int c = 0; c < nch; ++c) {
            const int kb = c * 32;
            __syncthreads();
#pragma unroll
            for (int p = 0; p < 2; ++p) {
                int idx = tid + p * 256;
                int r = idx >> 2;
                int c8 = (idx & 3) * 8;
                int m = m0 + r;
                if (m >= M) m = M - 1;
                *(uint4*)&As[r][c8] = *(const uint4*)(Ap + (size_t)m * lda + kb + c8);
                *(uint4*)&Wsh[r][c8] = *(const uint4*)(Wp + (size_t)(n0 + r) * K + kb + c8);
            }
            __syncthreads();

            bf16x8_t af[4], wf[4];
#pragma unroll
            for (int i = 0; i < 4; ++i)
                af[i] = *(const bf16x8_t*)&As[wm * 64 + i * 16 + lr][k0];
#pragma unroll
            for (int j = 0; j < 4; ++j)
                wf[j] = *(const bf16x8_t*)&Wsh[wn * 64 + j * 16 + lr][k0];
#pragma unroll
            for (int i = 0; i < 4; ++i)
#pragma unroll
                for (int j = 0; j < 4; ++j)
                    acc[i][j] = __builtin_amdgcn_mfma_f32_16x16x32_bf16(
                        af[i], wf[j], acc[i][j], 0, 0, 0);
        }
    }

    // epilogue
    const int lq = lane >> 4;
#pragma unroll
    for (int j = 0; j < 4; ++j) {
        int col = n0 + wn * 64 + j * 16 + lr;
        float bj = 0.f;
        if (b1) bj += b1[col];
        if (b2) bj += b2[col];
#pragma unroll
        for (int i = 0; i < 4; ++i) {
            int rowBase = m0 + wm * 64 + i * 16 + lq * 4;
#pragma unroll
            for (int r = 0; r < 4; ++r) {
                int gm = rowBase + r;
                if (gm >= M) continue;
                float v = acc[i][j][r] + bj;
                if (cnt) v *= (float)cnt[gm];
                if (outbf) {
                    ((unsigned short*)C)[(size_t)gm * ldc + col] = f2bf(v);
                } else {
                    float* p = (float*)C + (size_t)gm * ldc + col;
                    if (accf) *p += v; else *p = v;
                }
            }
        }
    }
}

// ---------------------------------------------------------------------------
extern "C" void kernel_launch(void* const* d_in, const int* in_sizes, int n_in,
                              void* d_out, int out_size, void* d_ws, size_t ws_size,
                              hipStream_t stream) {
    const float* x    = (const float*)d_in[0];
    const float* xb   = (const float*)d_in[1];
    const float* u    = (const float*)d_in[2];
    const int*   ei   = (const int*)d_in[3];
    const int*   eb   = (const int*)d_in[4];
    const int*   ec   = (const int*)d_in[5];
    const int*   bidx = (const int*)d_in[6];
    const int*   cidx = (const int*)d_in[7];
    const float* W_ii = (const float*)d_in[8];   const float* b_ii = (const float*)d_in[9];
    const float* W_bi = (const float*)d_in[10];  const float* b_bi = (const float*)d_in[11];
    const float* W_ci = (const float*)d_in[12];  const float* b_ci = (const float*)d_in[13];
    const float* W_bb = (const float*)d_in[14];  const float* b_bb = (const float*)d_in[15];
    const float* W_cc = (const float*)d_in[16];  const float* b_cc = (const float*)d_in[17];
    const float* W_im = (const float*)d_in[18];  const float* b_im = (const float*)d_in[19];
    const float* W_is = (const float*)d_in[20];  const float* b_is = (const float*)d_in[21];
    const float* W_bm = (const float*)d_in[22];  const float* b_bm = (const float*)d_in[23];
    const float* W_bs = (const float*)d_in[24];  const float* b_bs = (const float*)d_in[25];
    const float* W_cm = (const float*)d_in[26];  const float* b_cm = (const float*)d_in[27];
    const float* W_cs = (const float*)d_in[28];  const float* b_cs = (const float*)d_in[29];

    float* out = (float*)d_out;
    float* ws  = (float*)d_ws;

    // ---- ws layout: S fp32 [50000x128] first, then bf16 region -----------
    float* S = ws;                                     // 25.6 MB
    unsigned short* bfr = (unsigned short*)(ws + 6400000);
    unsigned short* x_bf  = bfr;                        // 6.4M
    unsigned short* xb_bf = bfr + 6400000;              // 2.56M
    unsigned short* u_bf  = bfr + 8960000;              // 0.64M
    unsigned short* A_bf  = bfr + 9600000;              // 6.4M
    unsigned short* xbp   = bfr + 16000000;             // 2.56M (reused as sb)
    unsigned short* ucp   = bfr + 18560000;             // 1.28M (reused as sc)
    unsigned short* wbuf  = bfr + 19840000;             // 294912
    // total ws: 65.9 MB

    // weight sub-offsets (ushorts)
    enum {
        O_wAii = 0,        O_wBii = 16384,  O_wBbi = 32768,  O_wBci = 49152,
        O_wAbi = 65536,    O_wAci = 81920,  O_wis  = 90112,  O_wim  = 122880,
        O_wbbs = 155648,   O_wbs  = 172032, O_wbm  = 204800, O_wccs = 237568,
        O_wcs  = 245760,   O_wcm  = 262144
    };

    // ---- int scratch in d_out boundary region (overwritten at the end) ----
    int* I       = (int*)(out + (size_t)NI * 256);
    int* ci      = I;
    int* cb      = I + 50000;
    int* cc      = I + 100000;
    int* offsets = I + 150000;
    int* cursor  = I + 200000;
    int* bsum    = I + 250000;   // 256
    int* ebase   = I + 250256;   // 256
    int* eids    = I + 250512;   // 530000

    // ---- 1. weight prep (one launch, 14 jobs) ----
    WJobs JB;
    auto setj = [&](int i, const float* s, int st, int o, int o2, int N, int K, int d) {
        JB.j[i].src = s; JB.j[i].stride = st; JB.j[i].off = o; JB.j[i].off2 = o2;
        JB.j[i].N = N; JB.j[i].K = K; JB.j[i].dstOff = d;
    };
    setj(0,  W_ii, 256, 0,   -1, 128, 128, O_wAii);
    setj(1,  W_ii, 256, 128, -1, 128, 128, O_wBii);
    setj(2,  W_bi, 256, 128, -1, 128, 128, O_wBbi);
    setj(3,  W_ci, 192, 64,  -1, 128, 128, O_wBci);
    setj(4,  W_bi, 256, 0,   -1, 128, 128, O_wAbi);
    setj(5,  W_ci, 192, 0,   -1, 128, 64,  O_wAci);
    setj(6,  W_is, 128, 0,   -1, 256, 128, O_wis);
    setj(7,  W_im, 128, 0,   -1, 256, 128, O_wim);
    setj(8,  W_bb, 256, 0,  128, 128, 128, O_wbbs);
    setj(9,  W_bs, 128, 0,   -1, 256, 128, O_wbs);
    setj(10, W_bm, 128, 0,   -1, 256, 128, O_wbm);
    setj(11, W_cc, 128, 0,   64, 128, 64,  O_wccs);
    setj(12, W_cs, 64,  0,   -1, 256, 64,  O_wcs);
    setj(13, W_cm, 128, 0,   -1, 256, 128, O_wcm);
    prep_weights_kernel<<<dim3(128, 14), dim3(256), 0, stream>>>(JB, wbuf);

    // ---- 2. input conversion ----
    conv_inputs_kernel<<<dim3((2400000 + 255) / 256), dim3(256), 0, stream>>>(
        (const float4*)x, (const float4*)xb, (const float4*)u,
        (ushort4*)x_bf, (ushort4*)xb_bf, (ushort4*)u_bf);

    // ---- 3. counts + parallel scan + CSR fill ----
    zero_counts_kernel<<<dim3((3 * NI + 255) / 256), dim3(256), 0, stream>>>(ci);
    count_kernel<<<dim3((E_TOT + 255) / 256), dim3(256), 0, stream>>>(
        ei, eb, ec, bidx, cidx, ci, cb, cc);
    scan1_kernel<<<dim3(SCAN_NB), dim3(256), 0, stream>>>(ci, cb, cc, bsum);
    scan2_kernel<<<dim3(1), dim3(256), 0, stream>>>(bsum, ebase);
    scan3_kernel<<<dim3(SCAN_NB), dim3(256), 0, stream>>>(ci, cb, cc, ebase,
                                                          offsets, cursor);
    fill_kernel<<<dim3((E_TOT + 255) / 256), dim3(256), 0, stream>>>(
        ei, eb, ec, bidx, cidx, cursor, eids);

    auto G = [&](const unsigned short* A1, int lda1, int K1, const unsigned short* W1,
                 const unsigned short* A2, int lda2, int K2, const unsigned short* W2,
                 const float* bb1, const float* bb2, const int* cnt, int accf, int outbf,
                 void* C, int M, int N, int ldc) {
        mfma_gemm_kernel<<<dim3((M + 127) / 128, N / 128), dim3(256), 0, stream>>>(
            A1, lda1, K1, W1, A2, lda2, K2, W2, bb1, bb2, cnt, accf, outbf, C, M, ldc);
    };

    // ---- 4. tables: A = x@W_iiA.T ; xbp = xb@W_biA.T ; ucp = u@W_ciA.T ----
    G(x_bf, 128, 128, wbuf + O_wAii, nullptr, 0, 0, nullptr,
      nullptr, nullptr, nullptr, 0, 1, A_bf, NI, 128, 128);
    G(xb_bf, 128, 128, wbuf + O_wAbi, nullptr, 0, 0, nullptr,
      nullptr, nullptr, nullptr, 0, 1, xbp, E_BN, 128, 128);
    G(u_bf, 64, 64, wbuf + O_wAci, nullptr, 0, 0, nullptr,
      nullptr, nullptr, nullptr, 0, 1, ucp, E_CN, 128, 128);

    // ---- 5. S = ci*(x@W_iiB.T+b_ii) + cb*(x@W_biB.T+b_bi) + cc*(x@W_ciB.T+b_ci)
    G(x_bf, 128, 128, wbuf + O_wBii, nullptr, 0, 0, nullptr,
      b_ii, nullptr, ci, 0, 0, S, NI, 128, 128);
    G(x_bf, 128, 128, wbuf + O_wBbi, nullptr, 0, 0, nullptr,
      b_bi, nullptr, cb, 1, 0, S, NI, 128, 128);
    G(x_bf, 128, 128, wbuf + O_wBci, nullptr, 0, 0, nullptr,
      b_ci, nullptr, cc, 1, 0, S, NI, 128, 128);

    // ---- 6. gather edge rows into S, divide, write agg bf16 in place ----
    gather_kernel<<<dim3((NI * 16 + 255) / 256), dim3(256), 0, stream>>>(
        A_bf, xbp, ucp, offsets, ci, cb, cc, eids, S);

    // ---- 7. interior = x@W_is.T + b_is + agg@W_im.T + b_im ----
    G(x_bf, 128, 128, wbuf + O_wis, (const unsigned short*)S, 256, 128, wbuf + O_wim,
      b_is, b_im, nullptr, 0, 0, out, NI, 256, 256);

    // ---- 8. boundary: sb = xb@(WbbA+WbbB).T + b_bb ; out = xb@W_bs.T + sb@W_bm.T + b
    G(xb_bf, 128, 128, wbuf + O_wbbs, nullptr, 0, 0, nullptr,
      b_bb, nullptr, nullptr, 0, 1, xbp /*sb*/, E_BN, 128, 128);
    G(xb_bf, 128, 128, wbuf + O_wbs, xbp, 128, 128, wbuf + O_wbm,
      b_bs, b_bm, nullptr, 0, 0, out + (size_t)NI * 256, E_BN, 256, 256);

    // ---- 9. control: sc = u@(WccA+WccB).T + b_cc ; out = u@W_cs.T + sc@W_cm.T + b
    G(u_bf, 64, 64, wbuf + O_wccs, nullptr, 0, 0, nullptr,
      b_cc, nullptr, nullptr, 0, 1, ucp /*sc*/, E_CN, 128, 128);
    G(u_bf, 64, 64, wbuf + O_wcs, ucp, 128, 128, wbuf + O_wcm,
      b_cs, b_cm, nullptr, 0, 0, out + (size_t)(NI + E_BN) * 256, E_CN, 256, 256);
}

// Round 4
// 371.650 us; speedup vs baseline: 4.5884x; 1.2112x over previous
//
#include <hip/hip_runtime.h>

#define NI 50000
#define E_INTN 500000
#define E_BN 20000
#define E_CN 10000
#define E_TOT (E_INTN + E_BN + E_CN)

typedef __attribute__((ext_vector_type(8))) short bf16x8_t;
typedef __attribute__((ext_vector_type(4))) float f32x4_t;

__device__ __forceinline__ unsigned short f2bf(float f) {
    unsigned int u = __float_as_uint(f);
    unsigned int r = (u + 0x7FFFu + ((u >> 16) & 1u)) >> 16;
    return (unsigned short)r;
}
__device__ __forceinline__ float bf2f(unsigned int h) {
    return __uint_as_float(h << 16);
}

// ---------------------------------------------------------------------------
// weight prep: fp32 -> packed bf16 [N x K], optional second-slice add (off2)
struct WJob { const float* src; int stride, off, off2, N, K, dstOff; };
struct WJobs { WJob j[14]; };

__global__ __launch_bounds__(256) void prep_weights_kernel(WJobs jobs,
                                                           unsigned short* wbuf) {
    WJob jb = jobs.j[blockIdx.y];
    int idx = blockIdx.x * 256 + threadIdx.x;
    if (idx >= jb.N * jb.K) return;
    int n = idx / jb.K;
    int k = idx - n * jb.K;
    float v = jb.src[(size_t)n * jb.stride + jb.off + k];
    if (jb.off2 >= 0) v += jb.src[(size_t)n * jb.stride + jb.off2 + k];
    wbuf[jb.dstOff + (size_t)n * jb.K + k] = f2bf(v);
}

// stacked-GEMM per-column bias vectors (fp32)
__global__ __launch_bounds__(256) void prep_bias_kernel(const float* __restrict__ b_ii,
                                                        const float* __restrict__ b_bi,
                                                        const float* __restrict__ b_ci,
                                                        const float* __restrict__ b_bb,
                                                        const float* __restrict__ b_cc,
                                                        float* __restrict__ bias) {
    int t = blockIdx.x * 256 + threadIdx.x;
    if (t < 512) {
        float v = 0.f;
        if (t >= 384) v = b_ci[t - 384];
        else if (t >= 256) v = b_bi[t - 256];
        else if (t >= 128) v = b_ii[t - 128];
        bias[t] = v;                       // bias_x
    } else if (t < 768) {
        int c = t - 512;
        bias[512 + c] = (c < 128) ? 0.f : b_bb[c - 128];   // bias_xb
    } else if (t < 1024) {
        int c = t - 768;
        bias[768 + c] = (c < 128) ? 0.f : b_cc[c - 128];   // bias_u
    }
}

// ---------------------------------------------------------------------------
// convert x (6.4M), xb (2.56M), u (0.64M) fp32 -> bf16, float4-granular
__global__ __launch_bounds__(256) void conv_inputs_kernel(const float4* __restrict__ x,
                                                          const float4* __restrict__ xb,
                                                          const float4* __restrict__ u,
                                                          ushort4* __restrict__ x_bf,
                                                          ushort4* __restrict__ xb_bf,
                                                          ushort4* __restrict__ u_bf) {
    int g = blockIdx.x * 256 + threadIdx.x;
    const float4* src; ushort4* dst; int i;
    if (g < 1600000)      { src = x;  dst = x_bf;  i = g; }
    else if (g < 2240000) { src = xb; dst = xb_bf; i = g - 1600000; }
    else if (g < 2400000) { src = u;  dst = u_bf;  i = g - 2240000; }
    else return;
    float4 v = src[i];
    ushort4 o;
    o.x = f2bf(v.x); o.y = f2bf(v.y); o.z = f2bf(v.z); o.w = f2bf(v.w);
    dst[i] = o;
}

// ---------------------------------------------------------------------------
__global__ __launch_bounds__(256) void zero_counts_kernel(int* __restrict__ c) {
    int i = blockIdx.x * 256 + threadIdx.x;
    if (i < 3 * NI) c[i] = 0;
}

__global__ __launch_bounds__(256) void count_kernel(const int* __restrict__ ei,
                                                    const int* __restrict__ eb,
                                                    const int* __restrict__ ec,
                                                    const int* __restrict__ bidx,
                                                    const int* __restrict__ cidx,
                                                    int* __restrict__ ci,
                                                    int* __restrict__ cb,
                                                    int* __restrict__ cc) {
    int e = blockIdx.x * 256 + threadIdx.x;
    if (e < E_INTN) {
        atomicAdd(&ci[ei[E_INTN + e]], 1);
    } else if (e < E_INTN + E_BN) {
        int j = e - E_INTN;
        int s = eb[j];
        bool m = false;
#pragma unroll
        for (int k = 0; k < 16; ++k) m = m || (s == bidx[k]);
        if (m) atomicAdd(&cb[eb[E_BN + j]], 1);
    } else if (e < E_TOT) {
        int j = e - E_INTN - E_BN;
        int s = ec[j];
        bool m = false;
#pragma unroll
        for (int k = 0; k < 16; ++k) m = m || (s == cidx[k]);
        if (m) atomicAdd(&cc[ec[E_CN + j]], 1);
    }
}

// ---------------------------------------------------------------------------
#define SCAN_NB 196   // ceil(50000/256)

__global__ __launch_bounds__(256) void scan1_kernel(const int* __restrict__ ci,
                                                    const int* __restrict__ cb,
                                                    const int* __restrict__ cc,
                                                    int* __restrict__ bsum) {
    __shared__ int sm[256];
    int n = blockIdx.x * 256 + threadIdx.x;
    int d = (n < NI) ? ci[n] + cb[n] + cc[n] : 0;
    sm[threadIdx.x] = d;
    __syncthreads();
    for (int s = 128; s > 0; s >>= 1) {
        if (threadIdx.x < s) sm[threadIdx.x] += sm[threadIdx.x + s];
        __syncthreads();
    }
    if (threadIdx.x == 0) bsum[blockIdx.x] = sm[0];
}

__global__ __launch_bounds__(256) void scan2_kernel(const int* __restrict__ bsum,
                                                    int* __restrict__ ebase) {
    __shared__ int sm[256];
    int t = threadIdx.x;
    sm[t] = (t < SCAN_NB) ? bsum[t] : 0;
    __syncthreads();
    for (int d = 1; d < 256; d <<= 1) {
        int v = (t >= d) ? sm[t - d] : 0;
        __syncthreads();
        sm[t] += v;
        __syncthreads();
    }
    ebase[t] = (t > 0) ? sm[t - 1] : 0;
}

__global__ __launch_bounds__(256) void scan3_kernel(const int* __restrict__ ci,
                                                    const int* __restrict__ cb,
                                                    const int* __restrict__ cc,
                                                    const int* __restrict__ ebase,
                                                    int* __restrict__ offsets,
                                                    int* __restrict__ cursor) {
    __shared__ int sm[256];
    int t = threadIdx.x;
    int n = blockIdx.x * 256 + t;
    int d = (n < NI) ? ci[n] + cb[n] + cc[n] : 0;
    sm[t] = d;
    __syncthreads();
    for (int dd = 1; dd < 256; dd <<= 1) {
        int v = (t >= dd) ? sm[t - dd] : 0;
        __syncthreads();
        sm[t] += v;
        __syncthreads();
    }
    if (n < NI) {
        int excl = sm[t] - d + ebase[blockIdx.x];
        offsets[n] = excl;
        cursor[n] = excl;
    }
}

// ---------------------------------------------------------------------------
__global__ __launch_bounds__(256) void fill_kernel(const int* __restrict__ ei,
                                                   const int* __restrict__ eb,
                                                   const int* __restrict__ ec,
                                                   const int* __restrict__ bidx,
                                                   const int* __restrict__ cidx,
                                                   int* __restrict__ cursor,
                                                   int* __restrict__ eids) {
    int e = blockIdx.x * 256 + threadIdx.x;
    int t, payload;
    if (e < E_INTN) {
        t = ei[E_INTN + e];
        payload = ei[e];
    } else if (e < E_INTN + E_BN) {
        int j = e - E_INTN;
        int s = eb[j];
        bool m = false;
#pragma unroll
        for (int k = 0; k < 16; ++k) m = m || (s == bidx[k]);
        if (!m) return;
        t = eb[E_BN + j];
        payload = NI + j;
    } else if (e < E_TOT) {
        int j = e - E_INTN - E_BN;
        int s = ec[j];
        bool m = false;
#pragma unroll
        for (int k = 0; k < 16; ++k) m = m || (s == cidx[k]);
        if (!m) return;
        t = ec[E_CN + j];
        payload = NI + E_BN + j;
    } else {
        return;
    }
    int idx = atomicAdd(&cursor[t], 1);
    eids[idx] = payload;
}

// ---------------------------------------------------------------------------
// gather: 16 lanes/node, 8 elems/lane.
// base = ci*Yx[:,128:256] + cb*Yx[:,256:384] + cc*Yx[:,384:512]  (biases folded)
// + sum of CSR edge rows: A=Yx[:,0:128] (stride 512), xbp=Yxb[:,0:128] (stride
// 256), ucp=Yu[:,0:128] (stride 256). Divide by deg, write agg bf16 [NI x 128].
__global__ __launch_bounds__(256) void gather_kernel(
    const unsigned short* __restrict__ Yx,
    const unsigned short* __restrict__ Yxb,
    const unsigned short* __restrict__ Yu,
    const int* __restrict__ offsets,
    const int* __restrict__ ci, const int* __restrict__ cb,
    const int* __restrict__ cc, const int* __restrict__ eids,
    unsigned short* __restrict__ agg) {
    int g = blockIdx.x * 256 + threadIdx.x;
    int n = g >> 4;
    int lane = g & 15;
    if (n >= NI) return;
    int off = offsets[n];
    int di = ci[n], db = cb[n], dc = cc[n];
    int deg = di + db + dc;
    float fi = (float)di, fb = (float)db, fc = (float)dc;
    const unsigned short* yrow = Yx + (size_t)n * 512 + lane * 8;
    uint4 vi = *(const uint4*)(yrow + 128);
    uint4 vb = *(const uint4*)(yrow + 256);
    uint4 vc = *(const uint4*)(yrow + 384);
    float acc[8];
    acc[0] = fi * bf2f(vi.x & 0xffff) + fb * bf2f(vb.x & 0xffff) + fc * bf2f(vc.x & 0xffff);
    acc[1] = fi * bf2f(vi.x >> 16)    + fb * bf2f(vb.x >> 16)    + fc * bf2f(vc.x >> 16);
    acc[2] = fi * bf2f(vi.y & 0xffff) + fb * bf2f(vb.y & 0xffff) + fc * bf2f(vc.y & 0xffff);
    acc[3] = fi * bf2f(vi.y >> 16)    + fb * bf2f(vb.y >> 16)    + fc * bf2f(vc.y >> 16);
    acc[4] = fi * bf2f(vi.z & 0xffff) + fb * bf2f(vb.z & 0xffff) + fc * bf2f(vc.z & 0xffff);
    acc[5] = fi * bf2f(vi.z >> 16)    + fb * bf2f(vb.z >> 16)    + fc * bf2f(vc.z >> 16);
    acc[6] = fi * bf2f(vi.w & 0xffff) + fb * bf2f(vb.w & 0xffff) + fc * bf2f(vc.w & 0xffff);
    acc[7] = fi * bf2f(vi.w >> 16)    + fb * bf2f(vb.w >> 16)    + fc * bf2f(vc.w >> 16);
    for (int k = 0; k < deg; ++k) {
        int eid = eids[off + k];
        const unsigned short* row =
            (eid < NI) ? Yx + (size_t)eid * 512
          : (eid < NI + E_BN) ? Yxb + (size_t)(eid - NI) * 256
          : Yu + (size_t)(eid - NI - E_BN) * 256;
        uint4 d = *(const uint4*)(row + lane * 8);
        acc[0] += bf2f(d.x & 0xffff); acc[1] += bf2f(d.x >> 16);
        acc[2] += bf2f(d.y & 0xffff); acc[3] += bf2f(d.y >> 16);
        acc[4] += bf2f(d.z & 0xffff); acc[5] += bf2f(d.z >> 16);
        acc[6] += bf2f(d.w & 0xffff); acc[7] += bf2f(d.w >> 16);
    }
    float inv = 1.f / fmaxf((float)deg, 1.f);
    uint4 o;
    o.x = (unsigned)f2bf(acc[0] * inv) | ((unsigned)f2bf(acc[1] * inv) << 16);
    o.y = (unsigned)f2bf(acc[2] * inv) | ((unsigned)f2bf(acc[3] * inv) << 16);
    o.z = (unsigned)f2bf(acc[4] * inv) | ((unsigned)f2bf(acc[5] * inv) << 16);
    o.w = (unsigned)f2bf(acc[6] * inv) | ((unsigned)f2bf(acc[7] * inv) << 16);
    *(uint4*)(agg + (size_t)n * 128 + lane * 8) = o;
}

// ---------------------------------------------------------------------------
// bf16 MFMA GEMM: C[M,N] = A1@W1.T (+ A2@W2.T) + b1 + b2, opt bf16 output.
// A row-major bf16 (stride lda), W packed [N x K] bf16. 128x128 block tile,
// BK=32, 4 waves, 4x4 MFMA tiles. N multiple of 128; K multiple of 32.
__global__ __launch_bounds__(256) void mfma_gemm_kernel(
    const unsigned short* __restrict__ A1, int lda1, int K1,
    const unsigned short* __restrict__ W1,
    const unsigned short* __restrict__ A2, int lda2, int K2,
    const unsigned short* __restrict__ W2,
    const float* __restrict__ b1, const float* __restrict__ b2,
    int outbf, void* __restrict__ C, int M, int ldc) {
    __shared__ __align__(16) unsigned short As[128][40];
    __shared__ __align__(16) unsigned short Wsh[128][40];

    const int m0 = blockIdx.x * 128;
    const int n0 = blockIdx.y * 128;
    const int tid = threadIdx.x;
    const int wid = tid >> 6;
    const int wm = wid >> 1, wn = wid & 1;
    const int lane = tid & 63;
    const int lr = lane & 15;
    const int k0 = (lane >> 4) * 8;

    f32x4_t acc[4][4];
#pragma unroll
    for (int i = 0; i < 4; ++i)
#pragma unroll
        for (int j = 0; j < 4; ++j) {
            f32x4_t z = {0.f, 0.f, 0.f, 0.f};
            acc[i][j] = z;
        }

    for (int pass = 0; pass < 2; ++pass) {
        const unsigned short* Ap = (pass == 0) ? A1 : A2;
        if (Ap == nullptr) break;
        const unsigned short* Wp = (pass == 0) ? W1 : W2;
        const int lda = (pass == 0) ? lda1 : lda2;
        const int K   = (pass == 0) ? K1 : K2;
        const int nch = K >> 5;

        for (int c = 0; c < nch; ++c) {
            const int kb = c * 32;
            __syncthreads();
#pragma unroll
            for (int p = 0; p < 2; ++p) {
                int idx = tid + p * 256;
                int r = idx >> 2;
                int c8 = (idx & 3) * 8;
                int m = m0 + r;
                if (m >= M) m = M - 1;
                *(uint4*)&As[r][c8] = *(const uint4*)(Ap + (size_t)m * lda + kb + c8);
                *(uint4*)&Wsh[r][c8] = *(const uint4*)(Wp + (size_t)(n0 + r) * K + kb + c8);
            }
            __syncthreads();

            bf16x8_t af[4], wf[4];
#pragma unroll
            for (int i = 0; i < 4; ++i)
                af[i] = *(const bf16x8_t*)&As[wm * 64 + i * 16 + lr][k0];
#pragma unroll
            for (int j = 0; j < 4; ++j)
                wf[j] = *(const bf16x8_t*)&Wsh[wn * 64 + j * 16 + lr][k0];
#pragma unroll
            for (int i = 0; i < 4; ++i)
#pragma unroll
                for (int j = 0; j < 4; ++j)
                    acc[i][j] = __builtin_amdgcn_mfma_f32_16x16x32_bf16(
                        af[i], wf[j], acc[i][j], 0, 0, 0);
        }
    }

    const int lq = lane >> 4;
#pragma unroll
    for (int j = 0; j < 4; ++j) {
        int col = n0 + wn * 64 + j * 16 + lr;
        float bj = 0.f;
        if (b1) bj += b1[col];
        if (b2) bj += b2[col];
#pragma unroll
        for (int i = 0; i < 4; ++i) {
            int rowBase = m0 + wm * 64 + i * 16 + lq * 4;
#pragma unroll
            for (int r = 0; r < 4; ++r) {
                int gm = rowBase + r;
                if (gm >= M) continue;
                float v = acc[i][j][r] + bj;
                if (outbf) {
                    ((unsigned short*)C)[(size_t)gm * ldc + col] = f2bf(v);
                } else {
                    ((float*)C)[(size_t)gm * ldc + col] = v;
                }
            }
        }
    }
}

// ---------------------------------------------------------------------------
extern "C" void kernel_launch(void* const* d_in, const int* in_sizes, int n_in,
                              void* d_out, int out_size, void* d_ws, size_t ws_size,
                              hipStream_t stream) {
    const float* x    = (const float*)d_in[0];
    const float* xb   = (const float*)d_in[1];
    const float* u    = (const float*)d_in[2];
    const int*   ei   = (const int*)d_in[3];
    const int*   eb   = (const int*)d_in[4];
    const int*   ec   = (const int*)d_in[5];
    const int*   bidx = (const int*)d_in[6];
    const int*   cidx = (const int*)d_in[7];
    const float* W_ii = (const float*)d_in[8];   const float* b_ii = (const float*)d_in[9];
    const float* W_bi = (const float*)d_in[10];  const float* b_bi = (const float*)d_in[11];
    const float* W_ci = (const float*)d_in[12];  const float* b_ci = (const float*)d_in[13];
    const float* W_bb = (const float*)d_in[14];  const float* b_bb = (const float*)d_in[15];
    const float* W_cc = (const float*)d_in[16];  const float* b_cc = (const float*)d_in[17];
    const float* W_im = (const float*)d_in[18];  const float* b_im = (const float*)d_in[19];
    const float* W_is = (const float*)d_in[20];  const float* b_is = (const float*)d_in[21];
    const float* W_bm = (const float*)d_in[22];  const float* b_bm = (const float*)d_in[23];
    const float* W_bs = (const float*)d_in[24];  const float* b_bs = (const float*)d_in[25];
    const float* W_cm = (const float*)d_in[26];  const float* b_cm = (const float*)d_in[27];
    const float* W_cs = (const float*)d_in[28];  const float* b_cs = (const float*)d_in[29];

    float* out = (float*)d_out;
    unsigned short* bfr = (unsigned short*)d_ws;

    // ---- ws layout (ushort offsets); total ~99.3 MB (ws evidenced ~327 MB)
    unsigned short* x_bf  = bfr;                 //  6,400,000
    unsigned short* xb_bf = bfr + 6400000;       //  2,560,000
    unsigned short* u_bf  = bfr + 8960000;       //    640,000
    unsigned short* Yx    = bfr + 9600000;       // 25,600,000  [50000 x 512]
    unsigned short* Yxb   = bfr + 35200000;      //  5,120,000  [20000 x 256]
    unsigned short* Yu    = bfr + 40320000;      //  2,560,000  [10000 x 256]
    unsigned short* agg   = bfr + 42880000;      //  6,400,000  [50000 x 128]
    unsigned short* wbuf  = bfr + 49280000;      //    294,912
    float* bias  = (float*)(bfr + 49600000);     //  1024 fp32
    float* bias_x  = bias;
    float* bias_xb = bias + 512;
    float* bias_u  = bias + 768;

    // weight sub-offsets (ushorts in wbuf)
    enum {
        O_WX  = 0,       O_WXB = 65536,  O_WU  = 98304,
        O_wis = 114688,  O_wim = 147456, O_wbs = 180224,
        O_wbm = 212992,  O_wcs = 245760, O_wcm = 262144
    };

    // ---- int scratch in d_out boundary region (overwritten by final GEMM) ----
    int* I       = (int*)(out + (size_t)NI * 256);
    int* ci      = I;
    int* cb      = I + 50000;
    int* cc      = I + 100000;
    int* offsets = I + 150000;
    int* cursor  = I + 200000;
    int* bsum    = I + 250000;   // 256
    int* ebase   = I + 250256;   // 256
    int* eids    = I + 250512;   // 530000

    // ---- 1. weight prep ----
    WJobs JB;
    auto setj = [&](int i, const float* s, int st, int o, int o2, int N, int K, int d) {
        JB.j[i].src = s; JB.j[i].stride = st; JB.j[i].off = o; JB.j[i].off2 = o2;
        JB.j[i].N = N; JB.j[i].K = K; JB.j[i].dstOff = d;
    };
    setj(0,  W_ii, 256, 0,   -1, 128, 128, O_WX);           // A slice
    setj(1,  W_ii, 256, 128, -1, 128, 128, O_WX + 16384);   // Bii
    setj(2,  W_bi, 256, 128, -1, 128, 128, O_WX + 32768);   // Bbi
    setj(3,  W_ci, 192, 64,  -1, 128, 128, O_WX + 49152);   // Bci
    setj(4,  W_bi, 256, 0,   -1, 128, 128, O_WXB);          // xbp
    setj(5,  W_bb, 256, 0,  128, 128, 128, O_WXB + 16384);  // sb (A+B)
    setj(6,  W_ci, 192, 0,   -1, 128, 64,  O_WU);           // ucp
    setj(7,  W_cc, 128, 0,   64, 128, 64,  O_WU + 8192);    // sc (A+B)
    setj(8,  W_is, 128, 0,   -1, 256, 128, O_wis);
    setj(9,  W_im, 128, 0,   -1, 256, 128, O_wim);
    setj(10, W_bs, 128, 0,   -1, 256, 128, O_wbs);
    setj(11, W_bm, 128, 0,   -1, 256, 128, O_wbm);
    setj(12, W_cs, 64,  0,   -1, 256, 64,  O_wcs);
    setj(13, W_cm, 128, 0,   -1, 256, 128, O_wcm);
    prep_weights_kernel<<<dim3(128, 14), dim3(256), 0, stream>>>(JB, wbuf);
    prep_bias_kernel<<<dim3(4), dim3(256), 0, stream>>>(b_ii, b_bi, b_ci, b_bb, b_cc, bias);

    // ---- 2. input conversion ----
    conv_inputs_kernel<<<dim3((2400000 + 255) / 256), dim3(256), 0, stream>>>(
        (const float4*)x, (const float4*)xb, (const float4*)u,
        (ushort4*)x_bf, (ushort4*)xb_bf, (ushort4*)u_bf);

    // ---- 3. counts + parallel scan + CSR fill ----
    zero_counts_kernel<<<dim3((3 * NI + 255) / 256), dim3(256), 0, stream>>>(ci);
    count_kernel<<<dim3((E_TOT + 255) / 256), dim3(256), 0, stream>>>(
        ei, eb, ec, bidx, cidx, ci, cb, cc);
    scan1_kernel<<<dim3(SCAN_NB), dim3(256), 0, stream>>>(ci, cb, cc, bsum);
    scan2_kernel<<<dim3(1), dim3(256), 0, stream>>>(bsum, ebase);
    scan3_kernel<<<dim3(SCAN_NB), dim3(256), 0, stream>>>(ci, cb, cc, ebase,
                                                          offsets, cursor);
    fill_kernel<<<dim3((E_TOT + 255) / 256), dim3(256), 0, stream>>>(
        ei, eb, ec, bidx, cidx, cursor, eids);

    auto G = [&](const unsigned short* A1, int lda1, int K1, const unsigned short* W1,
                 const unsigned short* A2, int lda2, int K2, const unsigned short* W2,
                 const float* bb1, const float* bb2, int outbf,
                 void* C, int M, int N, int ldc) {
        mfma_gemm_kernel<<<dim3((M + 127) / 128, N / 128), dim3(256), 0, stream>>>(
            A1, lda1, K1, W1, A2, lda2, K2, W2, bb1, bb2, outbf, C, M, ldc);
    };

    // ---- 4. stacked forward GEMMs (biases folded per-column) ----
    G(x_bf, 128, 128, wbuf + O_WX, nullptr, 0, 0, nullptr,
      bias_x, nullptr, 1, Yx, NI, 512, 512);
    G(xb_bf, 128, 128, wbuf + O_WXB, nullptr, 0, 0, nullptr,
      bias_xb, nullptr, 1, Yxb, E_BN, 256, 256);
    G(u_bf, 64, 64, wbuf + O_WU, nullptr, 0, 0, nullptr,
      bias_u, nullptr, 1, Yu, E_CN, 256, 256);

    // ---- 5. gather: base from Y slices + CSR edge rows -> agg bf16 ----
    gather_kernel<<<dim3((NI * 16 + 255) / 256), dim3(256), 0, stream>>>(
        Yx, Yxb, Yu, offsets, ci, cb, cc, eids, agg);

    // ---- 6. final GEMMs ----
    G(x_bf, 128, 128, wbuf + O_wis, agg, 128, 128, wbuf + O_wim,
      b_is, b_im, 0, out, NI, 256, 256);
    G(xb_bf, 128, 128, wbuf + O_wbs, Yxb + 128, 256, 128, wbuf + O_wbm,
      b_bs, b_bm, 0, out + (size_t)NI * 256, E_BN, 256, 256);
    G(u_bf, 64, 64, wbuf + O_wcs, Yu + 128, 256, 128, wbuf + O_wcm,
      b_cs, b_cm, 0, out + (size_t)(NI + E_BN) * 256, E_CN, 256, 256);
}